// Round 1
// baseline (451.383 us; speedup 1.0000x reference)
//
#include <hip/hip_runtime.h>
#include <stdint.h>
#include <math.h>

#define SS 8
#define NBLK 8192
#define DIN 512
#define DOUT 256
#define GB 8              // graph blocks per WG
#define MT 64             // rows per WG
#define KSTEPS 16         // DIN / 32
#define VSTR 264          // anchor bf16 LDS stride
#define EPSN 1e-12f

typedef __bf16 bf16;
typedef __bf16 bf16x8 __attribute__((ext_vector_type(8)));
typedef float  f32x4  __attribute__((ext_vector_type(4)));

__device__ __forceinline__ bf16x8 cvt8(f32x4 lo, f32x4 hi) {
    bf16x8 r;
    r[0] = (bf16)lo[0]; r[1] = (bf16)lo[1]; r[2] = (bf16)lo[2]; r[3] = (bf16)lo[3];
    r[4] = (bf16)hi[0]; r[5] = (bf16)hi[1]; r[6] = (bf16)hi[2]; r[7] = (bf16)hi[3];
    return r;
}

// ---- prep: Wt = W_gcn^T in bf16 [n][k]; W_bil split into bf16 hi+lo ----
__global__ void prep_kernel(const float* __restrict__ W_gcn,
                            const float* __restrict__ W_bil,
                            bf16* __restrict__ Wt,
                            bf16* __restrict__ Wh,
                            bf16* __restrict__ Wl) {
    int idx = blockIdx.x * 256 + threadIdx.x;   // 196608 total
    if (idx < DIN * DOUT) {
        int k = idx >> 8, n = idx & 255;
        Wt[n * DIN + k] = (bf16)W_gcn[idx];
    } else {
        int j = idx - DIN * DOUT;               // < 65536
        float wv = W_bil[j];
        bf16 h = (bf16)wv;
        Wh[j] = h;
        Wl[j] = (bf16)(wv - (float)h);
    }
}

// m-split design: wave w owns rows w*16..w*16+15 (graph blocks 2w, 2w+1) and
// ALL 256 output columns. A and B fragments load global->reg directly; the
// K-loop has NO LDS and NO barriers — each wave is an independent pipelined
// stream. acc layout per MFMA 16x16x32: C[row=q*4+r][col=r15], row-in-block
// = (q&1)*4+r, gl = 2w + (q>>1).
__global__ __launch_bounds__(256, 2) void cola_fused5(
    const float* __restrict__ pos_x, const float* __restrict__ neg_x,
    const int* __restrict__ pos_src, const int* __restrict__ pos_dst,
    const float* __restrict__ pos_w,
    const int* __restrict__ neg_src, const int* __restrict__ neg_dst,
    const float* __restrict__ neg_w,
    const bf16* __restrict__ Wt, const bf16* __restrict__ Wh,
    const bf16* __restrict__ Wl,
    const float* __restrict__ b_gcn, const float* __restrict__ prelu_a,
    const float* __restrict__ b_bil, float* __restrict__ out)
{
    __shared__ float adjP[GB][SS][SS];                    // 2 KB
    __shared__ float adjN[GB][SS][SS];                    // 2 KB
    __shared__ float red[5 * GB];                         // ssqP|ssqA|ssqN|scoreP|scoreN
    __shared__ __align__(16) float pool_pos[GB * DOUT];   // 8 KB
    __shared__ __align__(16) float v_lds[GB * DOUT];      // 8 KB
    __shared__ __align__(16) bf16  ahs[GB * VSTR];        // 4.125 KB
    __shared__ __align__(16) bf16  als[GB * VSTR];        // 4.125 KB

    const int t    = threadIdx.x;
    const int wg   = blockIdx.x;
    const int w    = t >> 6;
    const int lane = t & 63;
    const int q    = lane >> 4;
    const int r15  = lane & 15;
    const int row0 = wg * MT;

    // ---- zero adjacency + reductions ----
    for (int i = t; i < GB * 64; i += 256) { ((float*)adjP)[i] = 0.f; ((float*)adjN)[i] = 0.f; }
    if (t < 5 * GB) red[t] = 0.f;
    __syncthreads();

    // ---- build weighted adjacency (edges block-contiguous, 64/block) ----
    {
        int2   sp2 = ((const int2*)pos_src)[wg * 256 + t];
        int2   dp2 = ((const int2*)pos_dst)[wg * 256 + t];
        float2 wp2 = ((const float2*)pos_w)[wg * 256 + t];
        int2   sn2 = ((const int2*)neg_src)[wg * 256 + t];
        int2   dn2 = ((const int2*)neg_dst)[wg * 256 + t];
        float2 wn2 = ((const float2*)neg_w)[wg * 256 + t];
        int gb = t >> 5;
        int base = (wg * GB + gb) * SS;
        atomicAdd(&adjP[gb][dp2.x - base][sp2.x - base], wp2.x);
        atomicAdd(&adjP[gb][dp2.y - base][sp2.y - base], wp2.y);
        atomicAdd(&adjN[gb][dn2.x - base][sn2.x - base], wn2.x);
        atomicAdd(&adjN[gb][dn2.y - base][sn2.y - base], wn2.y);
    }
    // adj visibility covered by the post-K-loop barrier

    // ================= K-loop: no LDS, no barriers, reg-prefetched ==========
    const float* aP = pos_x + (size_t)(row0 + w * 16 + r15) * DIN + q * 8;
    const float* aN = neg_x + (size_t)(row0 + w * 16 + r15) * DIN + q * 8;
    const bf16*  bW = Wt + (size_t)r15 * DIN + q * 8;

    f32x4 accp[16], accn[16];
#pragma unroll
    for (int j = 0; j < 16; ++j) {
        accp[j] = (f32x4){0.f, 0.f, 0.f, 0.f};
        accn[j] = (f32x4){0.f, 0.f, 0.f, 0.f};
    }

    f32x4 pl0 = *(const f32x4*)(aP);
    f32x4 ph0 = *(const f32x4*)(aP + 4);
    f32x4 nl0 = *(const f32x4*)(aN);
    f32x4 nh0 = *(const f32x4*)(aN + 4);

    for (int s = 0; s < KSTEPS; ++s) {
        const int s2 = (s + 1 < KSTEPS) ? s + 1 : s;
        // prefetch next A tile (HBM stream) first — 1-step rotation
        f32x4 pl1 = *(const f32x4*)(aP + s2 * 32);
        f32x4 ph1 = *(const f32x4*)(aP + s2 * 32 + 4);
        f32x4 nl1 = *(const f32x4*)(aN + s2 * 32);
        f32x4 nh1 = *(const f32x4*)(aN + s2 * 32 + 4);

        // B fragments, group 0 (identical addresses across all 4 waves -> L1 hit)
        bf16x8 b0[8];
#pragma unroll
        for (int j = 0; j < 8; ++j)
            b0[j] = *(const bf16x8*)(bW + (size_t)(j * 16) * DIN + s * 32);

        bf16x8 afp = cvt8(pl0, ph0);
        bf16x8 afn = cvt8(nl0, nh0);

        bf16x8 b1[8];
#pragma unroll
        for (int j = 0; j < 8; ++j)
            b1[j] = *(const bf16x8*)(bW + (size_t)((j + 8) * 16) * DIN + s * 32);

#pragma unroll
        for (int j = 0; j < 8; ++j) {
            accp[j] = __builtin_amdgcn_mfma_f32_16x16x32_bf16(afp, b0[j], accp[j], 0, 0, 0);
            accn[j] = __builtin_amdgcn_mfma_f32_16x16x32_bf16(afn, b0[j], accn[j], 0, 0, 0);
        }
#pragma unroll
        for (int j = 0; j < 8; ++j) {
            accp[j + 8] = __builtin_amdgcn_mfma_f32_16x16x32_bf16(afp, b1[j], accp[j + 8], 0, 0, 0);
            accn[j + 8] = __builtin_amdgcn_mfma_f32_16x16x32_bf16(afn, b1[j], accn[j + 8], 0, 0, 0);
        }
        pl0 = pl1; ph0 = ph1; nl0 = nl1; nh0 = nh1;
    }
    __syncthreads();   // adjacency visible; epilogue LDS region about to be written

    const float pa = *prelu_a;
    const int gl = 2 * w + (q >> 1);

    // ================= POS epilogue =================
    {
        float part = 0.f;
#pragma unroll
        for (int ni = 0; ni < 16; ++ni) {
            float r0, r1, r2, r3, r4, r5, r6, r7;
#pragma unroll
            for (int r = 0; r < 4; ++r) {
                float own = accp[ni][r];
                float oth = __shfl_xor(own, 16);
                float lo = ((q & 1) == 0) ? own : oth;
                float hi = ((q & 1) == 0) ? oth : own;
                if (r == 0) { r0 = lo; r4 = hi; }
                else if (r == 1) { r1 = lo; r5 = hi; }
                else if (r == 2) { r2 = lo; r6 = hi; }
                else            { r3 = lo; r7 = hi; }
            }
            int c = ni * 16 + r15;
            float bg = b_gcn[c];
            float pool = 0.f, anch = 0.f;
#pragma unroll
            for (int d = 0; d < 8; ++d) {
                const float* ar = &adjP[gl][d][0];
                float a = bg + ar[0]*r0 + ar[1]*r1 + ar[2]*r2 + ar[3]*r3
                             + ar[4]*r4 + ar[5]*r5 + ar[6]*r6 + ar[7]*r7;
                float h = (a >= 0.f) ? a : pa * a;
                if (d < 7) pool += h; else anch = h;
            }
            float pl = pool * (1.f / 7.f);
            if ((q & 1) == 0) {
                pool_pos[gl * DOUT + c] = pl;
                part += pl * pl;
            } else {
                bf16 hh = (bf16)anch;
                ahs[gl * VSTR + c] = hh;
                als[gl * VSTR + c] = (bf16)(anch - (float)hh);
                part += anch * anch;
            }
        }
        part += __shfl_xor(part, 8);
        part += __shfl_xor(part, 4);
        part += __shfl_xor(part, 2);
        part += __shfl_xor(part, 1);
        // unique 16-lane group per (gl, pool/anchor) -> plain store, no atomic
        if (r15 == 0) { if (q & 1) red[GB + gl] = part; else red[gl] = part; }
    }
    __syncthreads();

    // ================= v = W_bil . anchor  (3-term bf16 split MFMA) ===========
    {
        f32x4 accv[4];
#pragma unroll
        for (int ni = 0; ni < 4; ++ni) accv[ni] = (f32x4){0.f, 0.f, 0.f, 0.f};
        const int ga = (r15 & 7) * VSTR;        // rows 8..15 duplicate 0..7
#pragma unroll
        for (int ks = 0; ks < 8; ++ks) {
            bf16x8 ah_f = *(const bf16x8*)(ahs + ga + ks * 32 + q * 8);
            bf16x8 al_f = *(const bf16x8*)(als + ga + ks * 32 + q * 8);
#pragma unroll
            for (int ni = 0; ni < 4; ++ni) {
                int d = w * 64 + ni * 16 + r15;
                bf16x8 bh = *(const bf16x8*)(Wh + (size_t)d * DOUT + ks * 32 + q * 8);
                bf16x8 bl = *(const bf16x8*)(Wl + (size_t)d * DOUT + ks * 32 + q * 8);
                accv[ni] = __builtin_amdgcn_mfma_f32_16x16x32_bf16(ah_f, bh, accv[ni], 0, 0, 0);
                accv[ni] = __builtin_amdgcn_mfma_f32_16x16x32_bf16(al_f, bh, accv[ni], 0, 0, 0);
                accv[ni] = __builtin_amdgcn_mfma_f32_16x16x32_bf16(ah_f, bl, accv[ni], 0, 0, 0);
            }
        }
        float sp[4] = {0.f, 0.f, 0.f, 0.f};
        if (q < 2) {
#pragma unroll
            for (int ni = 0; ni < 4; ++ni) {
                int c = w * 64 + ni * 16 + r15;
#pragma unroll
                for (int r = 0; r < 4; ++r) {
                    int g = q * 4 + r;
                    v_lds[g * DOUT + c] = accv[ni][r];
                    sp[r] += accv[ni][r] * pool_pos[g * DOUT + c];
                }
            }
        }
#pragma unroll
        for (int r = 0; r < 4; ++r) {
            sp[r] += __shfl_xor(sp[r], 8);
            sp[r] += __shfl_xor(sp[r], 4);
            sp[r] += __shfl_xor(sp[r], 2);
            sp[r] += __shfl_xor(sp[r], 1);
        }
        if (q < 2 && r15 == 0) {
#pragma unroll
            for (int r = 0; r < 4; ++r) atomicAdd(&red[3 * GB + q * 4 + r], sp[r]);
        }
    }
    __syncthreads();

    // ================= NEG epilogue ===========================================
    {
        float part = 0.f;
#pragma unroll
        for (int ni = 0; ni < 16; ++ni) {
            float r0, r1, r2, r3, r4, r5, r6, r7;
#pragma unroll
            for (int r = 0; r < 4; ++r) {
                float own = accn[ni][r];
                float oth = __shfl_xor(own, 16);
                float lo = ((q & 1) == 0) ? own : oth;
                float hi = ((q & 1) == 0) ? oth : own;
                if (r == 0) { r0 = lo; r4 = hi; }
                else if (r == 1) { r1 = lo; r5 = hi; }
                else if (r == 2) { r2 = lo; r6 = hi; }
                else            { r3 = lo; r7 = hi; }
            }
            int c = ni * 16 + r15;
            float bg = b_gcn[c];
            float pool = 0.f;
#pragma unroll
            for (int d = 0; d < 7; ++d) {
                const float* ar = &adjN[gl][d][0];
                float a = bg + ar[0]*r0 + ar[1]*r1 + ar[2]*r2 + ar[3]*r3
                             + ar[4]*r4 + ar[5]*r5 + ar[6]*r6 + ar[7]*r7;
                float h = (a >= 0.f) ? a : pa * a;
                pool += h;
            }
            float pl = pool * (1.f / 7.f);
            part += ((q & 1) == 0) ? pl * v_lds[gl * DOUT + c] : pl * pl;
        }
        part += __shfl_xor(part, 8);
        part += __shfl_xor(part, 4);
        part += __shfl_xor(part, 2);
        part += __shfl_xor(part, 1);
        if (r15 == 0) { if (q & 1) red[2 * GB + gl] = part; else red[4 * GB + gl] = part; }
    }
    __syncthreads();

    // ================= finalize ===============================================
    if (t < GB) {
        float np = fmaxf(sqrtf(red[t]), EPSN);
        float na = fmaxf(sqrtf(red[GB + t]), EPSN);
        float nn = fmaxf(sqrtf(red[2 * GB + t]), EPSN);
        float bb = b_bil[0];
        out[wg * GB + t]        = red[3 * GB + t] / (np * na) + bb;
        out[NBLK + wg * GB + t] = red[4 * GB + t] / (nn * na) + bb;
    }
}

extern "C" void kernel_launch(void* const* d_in, const int* in_sizes, int n_in,
                              void* d_out, int out_size, void* d_ws, size_t ws_size,
                              hipStream_t stream) {
    const float* pos_x   = (const float*)d_in[0];
    const float* neg_x   = (const float*)d_in[1];
    const int*   pos_src = (const int*)d_in[2];
    const int*   pos_dst = (const int*)d_in[3];
    const float* pos_w   = (const float*)d_in[4];
    const int*   neg_src = (const int*)d_in[5];
    const int*   neg_dst = (const int*)d_in[6];
    const float* neg_w   = (const float*)d_in[7];
    const float* W_gcn   = (const float*)d_in[8];
    const float* b_gcn   = (const float*)d_in[9];
    const float* prelu_a = (const float*)d_in[10];
    const float* W_bil   = (const float*)d_in[11];
    const float* b_bil   = (const float*)d_in[12];
    float* outp = (float*)d_out;

    bf16* Wt = (bf16*)d_ws;                 // 256 KB
    bf16* Wh = Wt + DIN * DOUT;             // 128 KB
    bf16* Wl = Wh + DOUT * DOUT;            // 128 KB

    prep_kernel<<<(DIN * DOUT + DOUT * DOUT) / 256, 256, 0, stream>>>(W_gcn, W_bil, Wt, Wh, Wl);
    cola_fused5<<<NBLK / GB, 256, 0, stream>>>(
        pos_x, neg_x, pos_src, pos_dst, pos_w, neg_src, neg_dst, neg_w,
        Wt, Wh, Wl, b_gcn, prelu_a, b_bil, outp);
}

// Round 2
// 366.316 us; speedup vs baseline: 1.2322x; 1.2322x over previous
//
#include <hip/hip_runtime.h>
#include <stdint.h>
#include <math.h>

#define SS 8
#define NBLK 8192
#define DIN 512
#define DOUT 256
#define GB 8              // graph blocks per WG
#define MT 64             // rows per WG
#define BK 32             // K chunk
#define KSTEPS 16         // DIN/BK
#define VSTR 264          // anchor bf16 LDS stride
#define EPSN 1e-12f

typedef __bf16 bf16;
typedef __bf16 bf16x8 __attribute__((ext_vector_type(8)));
typedef float  f32x4  __attribute__((ext_vector_type(4)));

typedef __attribute__((address_space(3))) uint32_t       lds_u32;
typedef __attribute__((address_space(1))) const uint32_t g_u32;

__device__ __forceinline__ void dma16(const void* g, void* l) {
    // async global->LDS, 16 B per lane; LDS dest = wave-uniform base + lane*16
    __builtin_amdgcn_global_load_lds((g_u32*)g, (lds_u32*)l, 16, 0, 0);
}

__device__ __forceinline__ bf16x8 cvt8(f32x4 lo, f32x4 hi) {
    bf16x8 r;
    r[0] = (bf16)lo[0]; r[1] = (bf16)lo[1]; r[2] = (bf16)lo[2]; r[3] = (bf16)lo[3];
    r[4] = (bf16)hi[0]; r[5] = (bf16)hi[1]; r[6] = (bf16)hi[2]; r[7] = (bf16)hi[3];
    return r;
}

// ---- prep: Wt = W_gcn^T in bf16, K-STEP-TILED layout Wt[s][n][kk]
//      (s = k/32, kk = k%32): per-wave per-step B slice is contiguous ----
__global__ void prep_kernel(const float* __restrict__ W_gcn,
                            const float* __restrict__ W_bil,
                            bf16* __restrict__ Wt,
                            bf16* __restrict__ Wh,
                            bf16* __restrict__ Wl) {
    int idx = blockIdx.x * 256 + threadIdx.x;   // 196608 total
    if (idx < DIN * DOUT) {
        int k = idx >> 8, n = idx & 255;
        Wt[((size_t)(k >> 5) * DOUT + n) * BK + (k & 31)] = (bf16)W_gcn[idx];
    } else {
        int j = idx - DIN * DOUT;               // < 65536
        float wv = W_bil[j];
        bf16 h = (bf16)wv;
        Wh[j] = h;
        Wl[j] = (bf16)(wv - (float)h);
    }
}

// Structure: round-0 col-split (wave w owns cols w*64..w*64+63, all 64 rows).
// A (pos_x/neg_x) staged via async global_load_lds into a 3-stage LDS ring with
// counted-vmcnt raw barriers (A-DMA gets ~2 steps to land, never drained).
// B (Wt, step-tiled) lives in registers, prefetched 1 step ahead: one coalesced
// 1 KB global load per fragment. No bufB -> no 8-way LDS bank conflict.
__global__ __launch_bounds__(256, 2) void cola_fused6(
    const float* __restrict__ pos_x, const float* __restrict__ neg_x,
    const int* __restrict__ pos_src, const int* __restrict__ pos_dst,
    const float* __restrict__ pos_w,
    const int* __restrict__ neg_src, const int* __restrict__ neg_dst,
    const float* __restrict__ neg_w,
    const bf16* __restrict__ Wt, const bf16* __restrict__ Wh,
    const bf16* __restrict__ Wl,
    const float* __restrict__ b_gcn, const float* __restrict__ prelu_a,
    const float* __restrict__ b_bil, float* __restrict__ out)
{
    __shared__ __align__(16) float bufA[3][2][MT * BK];   // 3 stages x (pos,neg) fp32, 48 KB
    __shared__ float adjP[GB][SS][SS];                    // 2 KB
    __shared__ float adjN[GB][SS][SS];                    // 2 KB
    __shared__ float red[5 * GB];                         // ssqP|ssqA|ssqN|scoreP|scoreN

    // epilogue buffers aliased onto bufA stages (dead after K-loop + barrier)
    float* pool_pos = (float*)&bufA[0][0][0];             // 8 KB (stage 0 first half)
    float* v_lds    = pool_pos + GB * DOUT;               // 8 KB (stage 0 second half)
    bf16*  ahs      = (bf16*)&bufA[1][0][0];              // 4.125 KB (stage 1)
    bf16*  als      = ahs + GB * VSTR;                    // 4.125 KB

    const int t    = threadIdx.x;
    const int wg   = blockIdx.x;
    const int w    = t >> 6;
    const int lane = t & 63;
    const int q    = lane >> 4;
    const int r15  = lane & 15;
    const int row0 = wg * MT;

    // ---- zero adjacency + reductions ----
    for (int i = t; i < GB * 64; i += 256) { ((float*)adjP)[i] = 0.f; ((float*)adjN)[i] = 0.f; }
    if (t < 5 * GB) red[t] = 0.f;
    __syncthreads();

    // ---- build weighted adjacency (edges block-contiguous, 64/block) ----
    {
        int2   sp2 = ((const int2*)pos_src)[wg * 256 + t];
        int2   dp2 = ((const int2*)pos_dst)[wg * 256 + t];
        float2 wp2 = ((const float2*)pos_w)[wg * 256 + t];
        int2   sn2 = ((const int2*)neg_src)[wg * 256 + t];
        int2   dn2 = ((const int2*)neg_dst)[wg * 256 + t];
        float2 wn2 = ((const float2*)neg_w)[wg * 256 + t];
        int gl = t >> 5;
        int base = (wg * GB + gl) * SS;
        atomicAdd(&adjP[gl][dp2.x - base][sp2.x - base], wp2.x);
        atomicAdd(&adjP[gl][dp2.y - base][sp2.y - base], wp2.y);
        atomicAdd(&adjN[gl][dn2.x - base][sn2.x - base], wn2.x);
        atomicAdd(&adjN[gl][dn2.y - base][sn2.y - base], wn2.y);
    }
    // adj LDS-atomic visibility covered by first K-loop lgkmcnt(0)+barrier

    // ---- DMA lane mapping (A only) ----
    // chunk c covers rows c*8..c*8+7; lane: row = c*8+(lane>>3),
    // stored k-quarter = lane&7 holds actual quarter (lane&7)^(lane>>3)  (XOR swizzle)
    const int arow_off = lane >> 3;                 // 0..7
    const int akq      = (lane & 7) ^ arow_off;     // actual global quarter to fetch

    auto issueA = [&](int s, int bufi) {
        const int kbase = s * BK;
#pragma unroll
        for (int h = 0; h < 2; ++h) {
            int c = w * 2 + h;
            int row = c * 8 + arow_off;
            dma16(pos_x + (size_t)(row0 + row) * DIN + kbase + akq * 4,
                  &bufA[bufi][0][c * 256]);
            dma16(neg_x + (size_t)(row0 + row) * DIN + kbase + akq * 4,
                  &bufA[bufi][1][c * 256]);
        }
    };

    // B: step-tiled Wt; wave w's cols, fragment ni -> one contiguous 1 KB load
    auto loadB = [&](bf16x8* dst, int s) {
#pragma unroll
        for (int ni = 0; ni < 4; ++ni)
            dst[ni] = *(const bf16x8*)(Wt +
                ((size_t)s * DOUT + w * 64 + ni * 16 + r15) * BK + q * 8);
    };

    f32x4 accp[4][4], accn[4][4];
#pragma unroll
    for (int mi = 0; mi < 4; ++mi)
#pragma unroll
        for (int ni = 0; ni < 4; ++ni) {
            accp[mi][ni] = (f32x4){0.f, 0.f, 0.f, 0.f};
            accn[mi][ni] = (f32x4){0.f, 0.f, 0.f, 0.f};
        }

    bf16x8 breg[2][4];

    // ---- prologue: A(0), B(0), A(1)  (order matters for vmcnt counting) ----
    issueA(0, 0);
    loadB(breg[0], 0);
    issueA(1, 1);

    // ================= K-loop: counted vmcnt + raw barrier, 3-stage A ring ====
    // Steady state at iter-s wait: queue (old->new) = [.., B(s)x4, A(s+1)x4]
    //   -> vmcnt(4) guarantees A(s) and B(s) landed, keeps A(s+1) in flight.
    // Issues placed AFTER the barrier: recycled stage (s+2)%3 was last read at
    // compute(s-1), which all waves finished before this barrier. Safe (m152).
#pragma unroll
    for (int s = 0; s < KSTEPS; ++s) {
        if (s == KSTEPS - 1)
            asm volatile("s_waitcnt vmcnt(0) lgkmcnt(0)" ::: "memory");
        else
            asm volatile("s_waitcnt vmcnt(4) lgkmcnt(0)" ::: "memory");
        __builtin_amdgcn_s_barrier();
        __builtin_amdgcn_sched_barrier(0);

        if (s + 1 < KSTEPS) loadB(breg[(s + 1) & 1], s + 1);
        if (s + 2 < KSTEPS) issueA(s + 2, (s + 2) % 3);

        const int bufi = s % 3;
        const bf16x8* bfv = breg[s & 1];
        const int q0 = (2 * q) ^ (r15 & 7);      // stored quarter holding j=0..3
        const int q1 = q0 ^ 1;                   // stored quarter holding j=4..7
        bf16x8 afp[4], afn[4];
#pragma unroll
        for (int mi = 0; mi < 4; ++mi) {
            int m = mi * 16 + r15;
            f32x4 lo = *(const f32x4*)&bufA[bufi][0][m * BK + q0 * 4];
            f32x4 hi = *(const f32x4*)&bufA[bufi][0][m * BK + q1 * 4];
            afp[mi] = cvt8(lo, hi);
            lo = *(const f32x4*)&bufA[bufi][1][m * BK + q0 * 4];
            hi = *(const f32x4*)&bufA[bufi][1][m * BK + q1 * 4];
            afn[mi] = cvt8(lo, hi);
        }
#pragma unroll
        for (int mi = 0; mi < 4; ++mi)
#pragma unroll
            for (int ni = 0; ni < 4; ++ni) {
                accp[mi][ni] = __builtin_amdgcn_mfma_f32_16x16x32_bf16(
                    afp[mi], bfv[ni], accp[mi][ni], 0, 0, 0);
                accn[mi][ni] = __builtin_amdgcn_mfma_f32_16x16x32_bf16(
                    afn[mi], bfv[ni], accn[mi][ni], 0, 0, 0);
            }
    }
    __syncthreads();    // all bufA reads done before epilogue aliasing writes

    const float pa = *prelu_a;

    // ================= POS epilogue =================
#pragma unroll
    for (int mi = 0; mi < 4; ++mi) {
        const int gl = mi * 2 + (q >> 1);
        float part = 0.f;
#pragma unroll
        for (int ni = 0; ni < 4; ++ni) {
            float r0, r1, r2, r3, r4, r5, r6, r7;
#pragma unroll
            for (int r = 0; r < 4; ++r) {
                float own = accp[mi][ni][r];
                float oth = __shfl_xor(own, 16);
                float lo = ((q & 1) == 0) ? own : oth;
                float hi = ((q & 1) == 0) ? oth : own;
                if (r == 0) { r0 = lo; r4 = hi; }
                else if (r == 1) { r1 = lo; r5 = hi; }
                else if (r == 2) { r2 = lo; r6 = hi; }
                else            { r3 = lo; r7 = hi; }
            }
            int c = w * 64 + ni * 16 + r15;
            float bg = b_gcn[c];
            float pool = 0.f, anch = 0.f;
#pragma unroll
            for (int d = 0; d < 8; ++d) {
                const float* ar = &adjP[gl][d][0];
                float a = bg + ar[0]*r0 + ar[1]*r1 + ar[2]*r2 + ar[3]*r3
                             + ar[4]*r4 + ar[5]*r5 + ar[6]*r6 + ar[7]*r7;
                float h = (a >= 0.f) ? a : pa * a;
                if (d < 7) pool += h; else anch = h;
            }
            float pl = pool * (1.f / 7.f);
            if ((q & 1) == 0) {
                pool_pos[gl * DOUT + c] = pl;
                part += pl * pl;
            } else {
                bf16 hh = (bf16)anch;
                ahs[gl * VSTR + c] = hh;
                als[gl * VSTR + c] = (bf16)(anch - (float)hh);
                part += anch * anch;
            }
        }
        part += __shfl_xor(part, 8);
        part += __shfl_xor(part, 4);
        part += __shfl_xor(part, 2);
        part += __shfl_xor(part, 1);
        if (r15 == 0) atomicAdd((q & 1) ? &red[GB + gl] : &red[gl], part);
    }
    __syncthreads();

    // ================= v = W_bil . anchor  (3-term bf16 split MFMA) ===========
    {
        f32x4 accv[4];
#pragma unroll
        for (int ni = 0; ni < 4; ++ni) accv[ni] = (f32x4){0.f, 0.f, 0.f, 0.f};
        const int ga = (r15 & 7) * VSTR;        // rows 8..15 duplicate 0..7
#pragma unroll
        for (int ks = 0; ks < 8; ++ks) {
            bf16x8 ah_f = *(const bf16x8*)(ahs + ga + ks * 32 + q * 8);
            bf16x8 al_f = *(const bf16x8*)(als + ga + ks * 32 + q * 8);
#pragma unroll
            for (int ni = 0; ni < 4; ++ni) {
                int d = w * 64 + ni * 16 + r15;
                bf16x8 bh = *(const bf16x8*)(Wh + (size_t)d * DOUT + ks * 32 + q * 8);
                bf16x8 bl = *(const bf16x8*)(Wl + (size_t)d * DOUT + ks * 32 + q * 8);
                accv[ni] = __builtin_amdgcn_mfma_f32_16x16x32_bf16(ah_f, bh, accv[ni], 0, 0, 0);
                accv[ni] = __builtin_amdgcn_mfma_f32_16x16x32_bf16(al_f, bh, accv[ni], 0, 0, 0);
                accv[ni] = __builtin_amdgcn_mfma_f32_16x16x32_bf16(ah_f, bl, accv[ni], 0, 0, 0);
            }
        }
        float sp[4] = {0.f, 0.f, 0.f, 0.f};
        if (q < 2) {
#pragma unroll
            for (int ni = 0; ni < 4; ++ni) {
                int c = w * 64 + ni * 16 + r15;
#pragma unroll
                for (int r = 0; r < 4; ++r) {
                    int g = q * 4 + r;
                    v_lds[g * DOUT + c] = accv[ni][r];
                    sp[r] += accv[ni][r] * pool_pos[g * DOUT + c];
                }
            }
        }
#pragma unroll
        for (int r = 0; r < 4; ++r) {
            sp[r] += __shfl_xor(sp[r], 8);
            sp[r] += __shfl_xor(sp[r], 4);
            sp[r] += __shfl_xor(sp[r], 2);
            sp[r] += __shfl_xor(sp[r], 1);
        }
        if (q < 2 && r15 == 0) {
#pragma unroll
            for (int r = 0; r < 4; ++r) atomicAdd(&red[3 * GB + q * 4 + r], sp[r]);
        }
    }
    __syncthreads();

    // ================= NEG epilogue ===========================================
#pragma unroll
    for (int mi = 0; mi < 4; ++mi) {
        const int gl = mi * 2 + (q >> 1);
        float part = 0.f;
#pragma unroll
        for (int ni = 0; ni < 4; ++ni) {
            float r0, r1, r2, r3, r4, r5, r6, r7;
#pragma unroll
            for (int r = 0; r < 4; ++r) {
                float own = accn[mi][ni][r];
                float oth = __shfl_xor(own, 16);
                float lo = ((q & 1) == 0) ? own : oth;
                float hi = ((q & 1) == 0) ? oth : own;
                if (r == 0) { r0 = lo; r4 = hi; }
                else if (r == 1) { r1 = lo; r5 = hi; }
                else if (r == 2) { r2 = lo; r6 = hi; }
                else            { r3 = lo; r7 = hi; }
            }
            int c = w * 64 + ni * 16 + r15;
            float bg = b_gcn[c];
            float pool = 0.f;
#pragma unroll
            for (int d = 0; d < 7; ++d) {
                const float* ar = &adjN[gl][d][0];
                float a = bg + ar[0]*r0 + ar[1]*r1 + ar[2]*r2 + ar[3]*r3
                             + ar[4]*r4 + ar[5]*r5 + ar[6]*r6 + ar[7]*r7;
                float h = (a >= 0.f) ? a : pa * a;
                pool += h;
            }
            float pl = pool * (1.f / 7.f);
            part += ((q & 1) == 0) ? pl * v_lds[gl * DOUT + c] : pl * pl;
        }
        part += __shfl_xor(part, 8);
        part += __shfl_xor(part, 4);
        part += __shfl_xor(part, 2);
        part += __shfl_xor(part, 1);
        if (r15 == 0) atomicAdd((q & 1) ? &red[2 * GB + gl] : &red[4 * GB + gl], part);
    }
    __syncthreads();

    // ================= finalize ===============================================
    if (t < GB) {
        float np = fmaxf(sqrtf(red[t]), EPSN);
        float na = fmaxf(sqrtf(red[GB + t]), EPSN);
        float nn = fmaxf(sqrtf(red[2 * GB + t]), EPSN);
        float bb = b_bil[0];
        out[wg * GB + t]        = red[3 * GB + t] / (np * na) + bb;
        out[NBLK + wg * GB + t] = red[4 * GB + t] / (nn * na) + bb;
    }
}

extern "C" void kernel_launch(void* const* d_in, const int* in_sizes, int n_in,
                              void* d_out, int out_size, void* d_ws, size_t ws_size,
                              hipStream_t stream) {
    const float* pos_x   = (const float*)d_in[0];
    const float* neg_x   = (const float*)d_in[1];
    const int*   pos_src = (const int*)d_in[2];
    const int*   pos_dst = (const int*)d_in[3];
    const float* pos_w   = (const float*)d_in[4];
    const int*   neg_src = (const int*)d_in[5];
    const int*   neg_dst = (const int*)d_in[6];
    const float* neg_w   = (const float*)d_in[7];
    const float* W_gcn   = (const float*)d_in[8];
    const float* b_gcn   = (const float*)d_in[9];
    const float* prelu_a = (const float*)d_in[10];
    const float* W_bil   = (const float*)d_in[11];
    const float* b_bil   = (const float*)d_in[12];
    float* outp = (float*)d_out;

    bf16* Wt = (bf16*)d_ws;                 // 256 KB (step-tiled)
    bf16* Wh = Wt + DIN * DOUT;             // 128 KB
    bf16* Wl = Wh + DOUT * DOUT;            // 128 KB

    prep_kernel<<<(DIN * DOUT + DOUT * DOUT) / 256, 256, 0, stream>>>(W_gcn, W_bil, Wt, Wh, Wl);
    cola_fused6<<<NBLK / GB, 256, 0, stream>>>(
        pos_x, neg_x, pos_src, pos_dst, pos_w, neg_src, neg_dst, neg_w,
        Wt, Wh, Wl, b_gcn, prelu_a, b_bil, outp);
}